// Round 2
// baseline (156.327 us; speedup 1.0000x reference)
//
#include <hip/hip_runtime.h>
#include <math.h>

// Problem shape (fixed by the reference): B=4, S=4, N=2048, D=2048
#define NB 4
#define NS 4
#define NN 2048
#define ND 2048
#define NTHREADS 512
#define SQRT_D 45.254833995939045f   // sqrt(2048)

typedef float f32x4 __attribute__((ext_vector_type(4)));

__global__ __launch_bounds__(NTHREADS, 6)
void hyperconn_kernel(const float* __restrict__ residuals,
                      const float* __restrict__ gamma,
                      const float* __restrict__ w_alpha,
                      const float* __restrict__ scale_alpha,
                      const float* __restrict__ static_alpha,
                      const float* __restrict__ w_beta,
                      const float* __restrict__ scale_beta,
                      const float* __restrict__ static_beta,
                      float* __restrict__ out)
{
    __shared__ float lds_x[NS * ND];   // 32 KB: the 4 input rows for this (b,n)
    __shared__ float red[8][8];        // per-wave partial sums (7 used)
    __shared__ float asb[NS][6];       // [s][0..4]=alpha row, [s][5]=beta

    const int tid  = threadIdx.x;
    const int bn   = blockIdx.x;          // 0 .. NB*NN-1
    const int b    = bn >> 11;
    const int n    = bn & (NN - 1);
    const int r    = tid >> 7;            // row 0..3 (one row per 128-thread group)
    const int u    = tid & 127;           // index within row group
    const int wave = tid >> 6;
    const int lane = tid & 63;

    const size_t row_stride = (size_t)NN * ND;
    const float* xrow = residuals + (size_t)(b * NS + r) * row_stride + (size_t)n * ND;

    // ---- Phase 1: load row r (streaming), stash in LDS, accumulate 7 partials ----
    // acc[0] = ssq(x); acc[1+j] = dot(x*(1+gamma), w_j)  j=0..4: w_alpha rows, j=5: w_beta
    float acc[7];
#pragma unroll
    for (int k = 0; k < 7; ++k) acc[k] = 0.f;

#pragma unroll
    for (int c = 0; c < 4; ++c) {
        const int d = c * 512 + u * 4;
        f32x4 x4 = __builtin_nontemporal_load((const f32x4*)(xrow + d));
        *reinterpret_cast<f32x4*>(&lds_x[r * ND + d]) = x4;

        f32x4 g4 = *reinterpret_cast<const f32x4*>(gamma + d);
        f32x4 xg = x4 + x4 * g4;          // x * (1 + gamma)

#pragma unroll
        for (int e = 0; e < 4; ++e) acc[0] += x4[e] * x4[e];

#pragma unroll
        for (int j = 0; j < 6; ++j) {
            const float* wsrc = (j < 5) ? (w_alpha + (size_t)j * ND + d) : (w_beta + d);
            f32x4 w4 = *reinterpret_cast<const f32x4*>(wsrc);
#pragma unroll
            for (int e = 0; e < 4; ++e) acc[1 + j] += xg[e] * w4[e];
        }
    }

    // ---- Phase 2: wave butterfly (7 values, not 28) ----
#pragma unroll
    for (int k = 0; k < 7; ++k) {
        float v = acc[k];
        v += __shfl_xor(v, 1);
        v += __shfl_xor(v, 2);
        v += __shfl_xor(v, 4);
        v += __shfl_xor(v, 8);
        v += __shfl_xor(v, 16);
        v += __shfl_xor(v, 32);
        acc[k] = v;
    }
    if (lane == 0) {
#pragma unroll
        for (int k = 0; k < 7; ++k) red[wave][k] = acc[k];
    }
    __syncthreads();

    // ---- Prefetch apply-phase x from LDS (overlaps the tanh tail) ----
    const int d4 = tid * 4;               // 512 threads cover all 2048 d-positions
    float xr[NS][4];
#pragma unroll
    for (int si = 0; si < NS; ++si)
        *reinterpret_cast<f32x4*>(&xr[si][0]) =
            *reinterpret_cast<const f32x4*>(&lds_x[si * ND + d4]);

    // ---- Phase 3: 24 threads, one tanh each ----
    if (tid < 24) {
        const int s = tid / 6;
        const int j = tid % 6;
        const float ssq = red[2 * s][0] + red[2 * s + 1][0];
        const float dot = red[2 * s][1 + j] + red[2 * s + 1][1 + j];
        const float rs  = SQRT_D / fmaxf(sqrtf(ssq), 1e-12f);
        const float th  = tanhf(dot * rs);
        asb[s][j] = (j < 5) ? (th * scale_alpha[0] + static_alpha[s * 5 + j])
                            : (th * scale_beta[0]  + static_beta[s]);
    }
    __syncthreads();

    // ---- M[so][si] = beta[so]*alpha[si][0] + alpha[si][so+1] (broadcast reads) ----
    float M[NS][NS];
#pragma unroll
    for (int so = 0; so < NS; ++so)
#pragma unroll
        for (int si = 0; si < NS; ++si)
            M[so][si] = asb[so][5] * asb[si][0] + asb[si][so + 1];

    // ---- Phase 4: out[so][d] = sum_si M[so][si] * x[si][d] ----
    float* obase = out + (size_t)(b * NS) * row_stride + (size_t)n * ND + d4;
#pragma unroll
    for (int so = 0; so < NS; ++so) {
        f32x4 o;
#pragma unroll
        for (int e = 0; e < 4; ++e) {
            o[e] = M[so][0] * xr[0][e] + M[so][1] * xr[1][e]
                 + M[so][2] * xr[2][e] + M[so][3] * xr[3][e];
        }
        __builtin_nontemporal_store(o, (f32x4*)(obase + (size_t)so * row_stride));
    }
}

extern "C" void kernel_launch(void* const* d_in, const int* in_sizes, int n_in,
                              void* d_out, int out_size, void* d_ws, size_t ws_size,
                              hipStream_t stream) {
    const float* residuals    = (const float*)d_in[0];
    const float* gamma        = (const float*)d_in[1];
    const float* w_alpha      = (const float*)d_in[2];
    const float* scale_alpha  = (const float*)d_in[3];
    const float* static_alpha = (const float*)d_in[4];
    const float* w_beta       = (const float*)d_in[5];
    const float* scale_beta   = (const float*)d_in[6];
    const float* static_beta  = (const float*)d_in[7];
    float* out = (float*)d_out;

    const int grid = NB * NN;  // 8192 blocks, one per (b, n)
    hyperconn_kernel<<<grid, NTHREADS, 0, stream>>>(
        residuals, gamma, w_alpha, scale_alpha, static_alpha,
        w_beta, scale_beta, static_beta, out);
}